// Round 4
// baseline (836.922 us; speedup 1.0000x reference)
//
#include <hip/hip_runtime.h>
#include <hip/hip_bf16.h>

#define IN_DIM 300
#define XDIM   320      // x row padded: 300 vals + bias-one at col 300 + zeros
#define MEM    1024
#define NTREE  16383
#define TAILNB 64       // persistent tail kernel blocks (<=256 -> co-resident)

typedef _Float16 half8 __attribute__((ext_vector_type(8)));
typedef float    f32x4 __attribute__((ext_vector_type(4)));

__device__ __forceinline__ float sigf(float x) { return 1.0f / (1.0f + __expf(-x)); }
__device__ __forceinline__ float tanhfast(float x) { return 2.0f / (1.0f + __expf(-2.0f * x)) - 1.0f; }

#define GLOAD_LDS16(g, l) \
    __builtin_amdgcn_global_load_lds((const __attribute__((address_space(1))) void*)(g), \
                                     (__attribute__((address_space(3))) void*)(l), 16, 0, 0)

// ---------------------------------------------------------------------------
// Pack (one-time): Wiou16 = [Wih;Woh;Wuh] (3072x1024 fp16), Wfh16 (1024x1024),
// x16 (16384x320: [x | 1.0 | 0...]), Bx (4096x320: [Wgx | bgx+bgh | 0...],
// rows g=i,o,u,f). Also zeroes the grid-barrier state (replay-safe).
// ---------------------------------------------------------------------------
__global__ void pack_kernel(
    const float* __restrict__ embs,
    const float* __restrict__ Wix, const float* __restrict__ bix,
    const float* __restrict__ Wih, const float* __restrict__ bih,
    const float* __restrict__ Wfx, const float* __restrict__ bfx,
    const float* __restrict__ Wfh, const float* __restrict__ bfh,
    const float* __restrict__ Wox, const float* __restrict__ box_,
    const float* __restrict__ Woh, const float* __restrict__ boh,
    const float* __restrict__ Wux, const float* __restrict__ bux,
    const float* __restrict__ Wuh, const float* __restrict__ buh,
    _Float16* __restrict__ Wiou16, _Float16* __restrict__ Wfh16,
    _Float16* __restrict__ x16, _Float16* __restrict__ Bx,
    unsigned* __restrict__ bar)
{
    if (blockIdx.x == 0 && threadIdx.x < 2) bar[threadIdx.x] = 0u;
    long long idx = (long long)blockIdx.x * blockDim.x + threadIdx.x;
    const long long n_wiou = 3072LL * 1024;
    const long long n_wfh  = 1024LL * 1024;
    const long long n_x    = 16384LL * XDIM;
    const long long n_bx   = 4096LL * XDIM;
    if (idx < n_wiou) {
        int m = (int)(idx >> 10), k = (int)(idx & 1023);
        int g = m >> 10, mm = m & 1023;
        const float* W = (g == 0) ? Wih : (g == 1) ? Woh : Wuh;
        Wiou16[idx] = (_Float16)W[(long long)mm * MEM + k];
        return;
    }
    idx -= n_wiou;
    if (idx < n_wfh) {
        Wfh16[idx] = (_Float16)Wfh[idx];
        return;
    }
    idx -= n_wfh;
    if (idx < n_x) {
        int node = (int)(idx / XDIM), j = (int)(idx % XDIM);
        float v = 0.f;
        if (node < NTREE) {
            if (j < IN_DIM) v = embs[(long long)node * IN_DIM + j];
            else if (j == IN_DIM) v = 1.0f;
        }
        x16[idx] = (_Float16)v;
        return;
    }
    idx -= n_x;
    if (idx < n_bx) {
        int r = (int)(idx / XDIM), j = (int)(idx % XDIM);
        int g = r >> 10, mm = r & 1023;
        const float* Wx = (g == 0) ? Wix : (g == 1) ? Wox : (g == 2) ? Wux : Wfx;
        const float* b1 = (g == 0) ? bix : (g == 1) ? box_ : (g == 2) ? bux : bfx;
        const float* b2 = (g == 0) ? bih : (g == 1) ? boh : (g == 2) ? buh : bfh;
        float v = 0.f;
        if (j < IN_DIM) v = Wx[(long long)mm * IN_DIM + j];
        else if (j == IN_DIM) v = b1[mm] + b2[mm];
        Bx[idx] = (_Float16)v;
    }
}

// ---------------------------------------------------------------------------
// GEMM tile core: C(BMxBN) = A(BMxK) * B(BNxK)^T. fp16 in / f32 MFMA / fp16
// out. 4 waves (2x2). SINGLE-buffered LDS, m97 2-barrier structure (dbuf
// regressed in r3: 64KB LDS -> occupancy 17%). BK=64 XOR swizzle (rule 21:
// linear LDS dest + inverse-swizzled global source + swizzled ds_read) keeps
// SQ_LDS_BANK_CONFLICT = 0 (verified r3).
// ---------------------------------------------------------------------------
template<int BM, int BN, int BK>
__device__ __forceinline__ void gemm_tile(
    const _Float16* __restrict__ A, int lda,
    const _Float16* __restrict__ B, int ldb,
    _Float16* __restrict__ C, int ldc, int K,
    _Float16* ldsA, _Float16* ldsB)
{
    constexpr int FM = BM / 32, FN = BN / 32;
    constexpr int CPR = BK / 8, SWM = CPR - 1;
    constexpr int ACH = BM * BK / 2048, BCH = BN * BK / 2048;

    int tid = threadIdx.x, wave = tid >> 6, lane = tid & 63;
    int wr = (wave >> 1) * (BM / 2), wc = (wave & 1) * (BN / 2);
    int kq = (lane >> 4) * 8, rs = lane & 15;
    f32x4 acc[FM][FN] = {};

    for (int k0 = 0; k0 < K; k0 += BK) {
#pragma unroll
        for (int j = 0; j < ACH; ++j) {
            int c = j * 256 + tid;
            int row = c / CPR;
            int s = (c ^ row) & SWM;
            GLOAD_LDS16(A + (long long)row * lda + k0 + s * 8,
                        &ldsA[(j * 256 + wave * 64) * 8]);
        }
#pragma unroll
        for (int j = 0; j < BCH; ++j) {
            int c = j * 256 + tid;
            int row = c / CPR;
            int s = (c ^ row) & SWM;
            GLOAD_LDS16(B + (long long)row * ldb + k0 + s * 8,
                        &ldsB[(j * 256 + wave * 64) * 8]);
        }
        __syncthreads();
#pragma unroll
        for (int kk = 0; kk < BK; kk += 32) {
            half8 a[FM], b[FN];
#pragma unroll
            for (int i = 0; i < FM; ++i) {
                int r = wr + i * 16 + rs;
                int s = ((kk + kq) >> 3) ^ (r & SWM);
                a[i] = *(const half8*)&ldsA[r * BK + s * 8];
            }
#pragma unroll
            for (int i = 0; i < FN; ++i) {
                int r = wc + i * 16 + rs;
                int s = ((kk + kq) >> 3) ^ (r & SWM);
                b[i] = *(const half8*)&ldsB[r * BK + s * 8];
            }
#pragma unroll
            for (int mi = 0; mi < FM; ++mi)
#pragma unroll
                for (int ni = 0; ni < FN; ++ni)
                    acc[mi][ni] = __builtin_amdgcn_mfma_f32_16x16x32_f16(a[mi], b[ni], acc[mi][ni], 0, 0, 0);
        }
        __syncthreads();
    }
    // C/D layout: col = lane&15, row = (lane>>4)*4 + reg  [m89-verified]
    int crb = wr + (lane >> 4) * 4, ccb = wc + rs;
#pragma unroll
    for (int mi = 0; mi < FM; ++mi)
#pragma unroll
        for (int i = 0; i < 4; ++i) {
            long long r = crb + mi * 16 + i;
#pragma unroll
            for (int ni = 0; ni < FN; ++ni)
                C[r * ldc + ccb + ni * 16] = (_Float16)acc[mi][ni][i];
        }
}

template<int BM, int BN, int BK>
__global__ __launch_bounds__(256) void gemm_f16(
    const _Float16* __restrict__ A, int lda,
    const _Float16* __restrict__ B, int ldb,
    _Float16* __restrict__ C, int ldc, int K)
{
    __shared__ __align__(16) _Float16 ldsA[BM * BK];
    __shared__ __align__(16) _Float16 ldsB[BN * BK];
    gemm_tile<BM, BN, BK>(A + (long long)blockIdx.x * BM * lda, lda,
                          B + (long long)blockIdx.y * BN * ldb, ldb,
                          C + (long long)blockIdx.x * BM * ldc + (long long)blockIdx.y * BN,
                          ldc, K, ldsA, ldsB);
}

// Fused per-level GEMM (big levels n>=512): part1 = hsum @ Wiou^T (n x 3072),
// part2 = H @ Wfh^T (2n x 1024). Both K=1024. 32 KB LDS.
__global__ __launch_bounds__(256) void gemm_level(
    const _Float16* __restrict__ Hsum, const _Float16* __restrict__ Hc,
    const _Float16* __restrict__ Wiou, const _Float16* __restrict__ Wf,
    _Float16* __restrict__ houpre, _Float16* __restrict__ fpre,
    int G1, int G2)
{
    __shared__ __align__(16) _Float16 ldsA[128 * 64];
    __shared__ __align__(16) _Float16 ldsB[128 * 64];
    int bx = blockIdx.x;
    if (bx < G1 * 24) {
        int nb = bx / G1, mb = bx % G1;
        gemm_tile<128, 128, 64>(Hsum + (long long)mb * 128 * 1024, 1024,
                                Wiou + (long long)nb * 128 * 1024, 1024,
                                houpre + (long long)mb * 128 * 3072 + nb * 128, 3072,
                                1024, ldsA, ldsB);
    } else {
        int b2 = bx - G1 * 24;
        int nb = b2 / G2, mb = b2 % G2;
        gemm_tile<128, 128, 64>(Hc + (long long)mb * 128 * 1024, 1024,
                                Wf + (long long)nb * 128 * 1024, 1024,
                                fpre + (long long)mb * 128 * 1024 + nb * 128, 1024,
                                1024, ldsA, ldsB);
    }
}

// ---------------------------------------------------------------------------
// Leaf fused GEMM+combine: tile 64 leaves x 128 cols, 3 gate accumulators
// (i,o,u), K=320, single-buffered (28 KB LDS). Writes cleaf/h/hsum.
// ---------------------------------------------------------------------------
__global__ __launch_bounds__(256) void leaf_fused(
    const _Float16* __restrict__ x16, const _Float16* __restrict__ Bx,
    _Float16* __restrict__ cleaf, _Float16* __restrict__ hleaf,
    _Float16* __restrict__ hsum)
{
    constexpr int BK = 32, CPR = 4, SWM = 3;
    __shared__ __align__(16) _Float16 lA[64 * BK];
    __shared__ __align__(16) _Float16 lB[384 * BK];
    int tid = threadIdx.x, wave = tid >> 6, lane = tid & 63;
    int kq = (lane >> 4) * 8, rs = lane & 15;
    int wr = (wave >> 1) * 32, wc = (wave & 1) * 64;
    int m0 = blockIdx.x * 64, c0 = blockIdx.y * 128;
    const _Float16* A = x16 + (size_t)(8191 + m0) * XDIM;

    f32x4 acc[3][2][4] = {};
    for (int t = 0; t < 10; ++t) {     // K = 320
        int k0 = t * BK;
        {   // A: 256 chunks, 1/thread
            int c = tid, row = c / CPR, s = (c ^ row) & SWM;
            GLOAD_LDS16(A + (long long)row * XDIM + k0 + s * 8, &lA[(wave * 64) * 8]);
        }
#pragma unroll
        for (int j = 0; j < 6; ++j) {   // B: 1536 chunks (3 gate tiles x 128)
            int c = j * 256 + tid;
            int row = c / CPR, s = (c ^ row) & SWM;
            int g = row >> 7, rr = row & 127;
            GLOAD_LDS16(Bx + (long long)(g * 1024 + c0 + rr) * XDIM + k0 + s * 8,
                        &lB[(j * 256 + wave * 64) * 8]);
        }
        __syncthreads();
        half8 a[2], b[3][4];
#pragma unroll
        for (int mi = 0; mi < 2; ++mi) {
            int r = wr + mi * 16 + rs;
            int s = (kq >> 3) ^ (r & SWM);
            a[mi] = *(const half8*)&lA[r * BK + s * 8];
        }
#pragma unroll
        for (int g = 0; g < 3; ++g)
#pragma unroll
            for (int nj = 0; nj < 4; ++nj) {
                int r = g * 128 + wc + nj * 16 + rs;
                int s = (kq >> 3) ^ (r & SWM);
                b[g][nj] = *(const half8*)&lB[r * BK + s * 8];
            }
#pragma unroll
        for (int g = 0; g < 3; ++g)
#pragma unroll
            for (int mi = 0; mi < 2; ++mi)
#pragma unroll
                for (int nj = 0; nj < 4; ++nj)
                    acc[g][mi][nj] = __builtin_amdgcn_mfma_f32_16x16x32_f16(a[mi], b[g][nj], acc[g][mi][nj], 0, 0, 0);
        __syncthreads();
    }
    int lrb = wr + (lane >> 4) * 4;
#pragma unroll
    for (int mi = 0; mi < 2; ++mi)
#pragma unroll
        for (int nj = 0; nj < 4; ++nj) {
            int col = c0 + wc + nj * 16 + rs;
            float hpair = 0.f;
#pragma unroll
            for (int i = 0; i < 4; ++i) {
                long long l = m0 + lrb + mi * 16 + i;
                float cc = sigf(acc[0][mi][nj][i]) * tanhfast(acc[2][mi][nj][i]);
                float hh = sigf(acc[1][mi][nj][i]) * tanhfast(cc);
                cleaf[l * 1024 + col] = (_Float16)cc;
                hleaf[l * 1024 + col] = (_Float16)hh;
                if (i & 1) hsum[(l >> 1) * 1024 + col] = (_Float16)(hpair + hh);
                else hpair = hh;
            }
        }
}

// ---------------------------------------------------------------------------
// Internal-level combine (big levels): gates from houpre + XpI, f per child
// from fpre + XpF(parent), c = i*u + f0*c0 + f1*c1, h = o*tanh(c).
// ---------------------------------------------------------------------------
template<bool C16>
__global__ void combine_level(
    const _Float16* __restrict__ houpre, const _Float16* __restrict__ fpre,
    const void* __restrict__ cprevp,
    const _Float16* __restrict__ XpI, const _Float16* __restrict__ XpF,
    float* __restrict__ cout, _Float16* __restrict__ hout, _Float16* __restrict__ hsum,
    int n, int gx0)
{
    int idx = blockIdx.x * blockDim.x + threadIdx.x;
    int npairs = n >> 1;
    if (idx >= npairs * 128) return;
    int r = idx >> 7, m8 = (idx & 127) * 8;
    float hs[8];
#pragma unroll
    for (int j = 0; j < 8; ++j) hs[j] = 0.f;
    for (int t = 0; t < 2; ++t) {
        int p = 2 * r + t;
        long long node = gx0 + p;
        half8 phi = *(const half8*)&houpre[(long long)p * 3072 + m8];
        half8 pho = *(const half8*)&houpre[(long long)p * 3072 + 1024 + m8];
        half8 phu = *(const half8*)&houpre[(long long)p * 3072 + 2048 + m8];
        half8 pxi = *(const half8*)&XpI[node * 3072 + m8];
        half8 pxo = *(const half8*)&XpI[node * 3072 + 1024 + m8];
        half8 pxu = *(const half8*)&XpI[node * 3072 + 2048 + m8];
        half8 pf0 = *(const half8*)&fpre[(long long)(2 * p) * 1024 + m8];
        half8 pf1 = *(const half8*)&fpre[(long long)(2 * p + 1) * 1024 + m8];
        half8 pxf = *(const half8*)&XpF[node * 1024 + m8];
        float c0[8], c1[8];
        if (C16) {
            const _Float16* cp = (const _Float16*)cprevp;
            half8 a = *(const half8*)&cp[(long long)(2 * p) * 1024 + m8];
            half8 b = *(const half8*)&cp[(long long)(2 * p + 1) * 1024 + m8];
#pragma unroll
            for (int j = 0; j < 8; ++j) { c0[j] = (float)a[j]; c1[j] = (float)b[j]; }
        } else {
            const float* cp = (const float*)cprevp;
            f32x4 a0 = *(const f32x4*)&cp[(long long)(2 * p) * 1024 + m8];
            f32x4 a1 = *(const f32x4*)&cp[(long long)(2 * p) * 1024 + m8 + 4];
            f32x4 b0 = *(const f32x4*)&cp[(long long)(2 * p + 1) * 1024 + m8];
            f32x4 b1 = *(const f32x4*)&cp[(long long)(2 * p + 1) * 1024 + m8 + 4];
#pragma unroll
            for (int j = 0; j < 4; ++j) { c0[j] = a0[j]; c0[j + 4] = a1[j]; c1[j] = b0[j]; c1[j + 4] = b1[j]; }
        }
        float cw[8], hw[8];
#pragma unroll
        for (int j = 0; j < 8; ++j) {
            float i  = sigf((float)phi[j] + (float)pxi[j]);
            float o  = sigf((float)pho[j] + (float)pxo[j]);
            float u  = tanhfast((float)phu[j] + (float)pxu[j]);
            float f0 = sigf((float)pf0[j] + (float)pxf[j]);
            float f1 = sigf((float)pf1[j] + (float)pxf[j]);
            float c = i * u + f0 * c0[j] + f1 * c1[j];
            float h = o * tanhfast(c);
            cw[j] = c; hw[j] = h; hs[j] += h;
        }
        f32x4 v0 = {cw[0], cw[1], cw[2], cw[3]}, v1 = {cw[4], cw[5], cw[6], cw[7]};
        *(f32x4*)&cout[(long long)p * 1024 + m8] = v0;
        *(f32x4*)&cout[(long long)p * 1024 + m8 + 4] = v1;
        half8 hv;
#pragma unroll
        for (int j = 0; j < 8; ++j) hv[j] = (_Float16)hw[j];
        *(half8*)&hout[(long long)p * 1024 + m8] = hv;
    }
    half8 sv;
#pragma unroll
    for (int j = 0; j < 8; ++j) sv[j] = (_Float16)hs[j];
    *(half8*)&hsum[(long long)r * 1024 + m8] = sv;
}

// ---------------------------------------------------------------------------
// Persistent tail (levels n<=256): one kernel, 64 co-resident blocks, software
// grid barrier between levels (agent-scope atomics + threadfence; state
// zeroed by pack_kernel each launch -> deterministic & replay-safe).
// ---------------------------------------------------------------------------
__device__ __forceinline__ void grid_barrier(unsigned* bar, unsigned nb)
{
    __syncthreads();
    __threadfence();
    if (threadIdx.x == 0) {
        unsigned g = __hip_atomic_load(&bar[1], __ATOMIC_RELAXED, __HIP_MEMORY_SCOPE_AGENT);
        unsigned v = __hip_atomic_fetch_add(&bar[0], 1u, __ATOMIC_ACQ_REL, __HIP_MEMORY_SCOPE_AGENT);
        if (v == nb - 1u) {
            __hip_atomic_store(&bar[0], 0u, __ATOMIC_RELAXED, __HIP_MEMORY_SCOPE_AGENT);
            __hip_atomic_fetch_add(&bar[1], 1u, __ATOMIC_ACQ_REL, __HIP_MEMORY_SCOPE_AGENT);
        } else {
            while (__hip_atomic_load(&bar[1], __ATOMIC_ACQUIRE, __HIP_MEMORY_SCOPE_AGENT) == g)
                __builtin_amdgcn_s_sleep(8);
        }
    }
    __syncthreads();
    __threadfence();
}

// One 64-parent x 64-col tile of a fused level: 5 MFMA groups (i,o,u from
// hsum; f-even/f-odd from child h), dbuf stage-early BK=32 (tail is
// latency-bound, occupancy irrelevant at <=64 blocks), combine epilogue.
__device__ void tail_tile(
    const _Float16* __restrict__ Hs, const _Float16* __restrict__ Hc,
    const _Float16* __restrict__ Wiou, const _Float16* __restrict__ Wf,
    const float* __restrict__ cprev,
    const _Float16* __restrict__ XpI, const _Float16* __restrict__ XpF,
    float* __restrict__ cout, _Float16* __restrict__ hout,
    _Float16* __restrict__ hsumout, int n, int gx0, float* __restrict__ fin,
    int p0, int c0, _Float16* lA, _Float16* lB)
{
    constexpr int BK = 32, CPR = 4, SWM = 3;
    int tid = threadIdx.x, wave = tid >> 6, lane = tid & 63;
    int kq = (lane >> 4) * 8, rs = lane & 15;
    int wr = (wave >> 1) * 32, wc = (wave & 1) * 32;

    auto stage = [&](int buf, int k0) {
#pragma unroll
        for (int j = 0; j < 3; ++j) {          // A: 768 chunks (hsum|heven|hodd)
            int c = j * 256 + tid;
            int row = c / CPR, s = (c ^ row) & SWM;
            int ta = row >> 6, rr = row & 63;
            const _Float16* src = (ta == 0) ? Hs : Hc;
            long long grow = (ta == 0) ? (long long)(p0 + rr)
                                       : (2LL * (p0 + rr) + (ta - 1));
            GLOAD_LDS16(src + grow * 1024 + k0 + s * 8,
                        &lA[buf * 192 * BK + (j * 256 + wave * 64) * 8]);
        }
#pragma unroll
        for (int j = 0; j < 4; ++j) {          // B: 1024 chunks (i|o|u|f, 64 rows)
            int c = j * 256 + tid;
            int row = c / CPR, s = (c ^ row) & SWM;
            int tb = row >> 6, rr = row & 63;
            const _Float16* src = (tb < 3) ? Wiou : Wf;
            long long grow = (tb < 3) ? (long long)(tb * 1024 + c0 + rr)
                                      : (long long)(c0 + rr);
            GLOAD_LDS16(src + grow * 1024 + k0 + s * 8,
                        &lB[buf * 256 * BK + (j * 256 + wave * 64) * 8]);
        }
    };
    f32x4 acc[5][2][2] = {};
    stage(0, 0);
    __syncthreads();
    for (int t = 0; t < 32; ++t) {             // K = 1024
        if (t + 1 < 32) stage((t + 1) & 1, (t + 1) * BK);
        const _Float16* bA = lA + (t & 1) * 192 * BK;
        const _Float16* bB = lB + (t & 1) * 256 * BK;
        half8 a[3][2], b[4][2];
#pragma unroll
        for (int ta = 0; ta < 3; ++ta)
#pragma unroll
            for (int mi = 0; mi < 2; ++mi) {
                int r = ta * 64 + wr + mi * 16 + rs;
                int s = (kq >> 3) ^ (r & SWM);
                a[ta][mi] = *(const half8*)&bA[r * BK + s * 8];
            }
#pragma unroll
        for (int tb = 0; tb < 4; ++tb)
#pragma unroll
            for (int nj = 0; nj < 2; ++nj) {
                int r = tb * 64 + wc + nj * 16 + rs;
                int s = (kq >> 3) ^ (r & SWM);
                b[tb][nj] = *(const half8*)&bB[r * BK + s * 8];
            }
#pragma unroll
        for (int mi = 0; mi < 2; ++mi)
#pragma unroll
            for (int nj = 0; nj < 2; ++nj) {
                acc[0][mi][nj] = __builtin_amdgcn_mfma_f32_16x16x32_f16(a[0][mi], b[0][nj], acc[0][mi][nj], 0, 0, 0);
                acc[1][mi][nj] = __builtin_amdgcn_mfma_f32_16x16x32_f16(a[0][mi], b[1][nj], acc[1][mi][nj], 0, 0, 0);
                acc[2][mi][nj] = __builtin_amdgcn_mfma_f32_16x16x32_f16(a[0][mi], b[2][nj], acc[2][mi][nj], 0, 0, 0);
                acc[3][mi][nj] = __builtin_amdgcn_mfma_f32_16x16x32_f16(a[1][mi], b[3][nj], acc[3][mi][nj], 0, 0, 0);
                acc[4][mi][nj] = __builtin_amdgcn_mfma_f32_16x16x32_f16(a[2][mi], b[3][nj], acc[4][mi][nj], 0, 0, 0);
            }
        __syncthreads();
    }
    int lrb = wr + (lane >> 4) * 4;
#pragma unroll
    for (int mi = 0; mi < 2; ++mi)
#pragma unroll
        for (int nj = 0; nj < 2; ++nj) {
            int col = c0 + wc + nj * 16 + rs;
            float hpair = 0.f;
#pragma unroll
            for (int i = 0; i < 4; ++i) {
                int p = p0 + lrb + mi * 16 + i;
                if (p >= n) continue;
                long long node = gx0 + p;
                float ip = acc[0][mi][nj][i] + (float)XpI[node * 3072 + col];
                float op = acc[1][mi][nj][i] + (float)XpI[node * 3072 + 1024 + col];
                float up = acc[2][mi][nj][i] + (float)XpI[node * 3072 + 2048 + col];
                float xf = (float)XpF[node * 1024 + col];
                float f0 = sigf(acc[3][mi][nj][i] + xf);
                float f1 = sigf(acc[4][mi][nj][i] + xf);
                float cc = sigf(ip) * tanhfast(up)
                         + f0 * cprev[(long long)(2 * p) * 1024 + col]
                         + f1 * cprev[(long long)(2 * p + 1) * 1024 + col];
                float hh = sigf(op) * tanhfast(cc);
                if (fin) {
                    if (p == 0) { fin[col] = cc; fin[1024 + col] = hh; }
                } else {
                    cout[(long long)p * 1024 + col] = cc;
                    hout[(long long)p * 1024 + col] = (_Float16)hh;
                    if (i & 1) hsumout[((long long)(p >> 1)) * 1024 + col] = (_Float16)(hpair + hh);
                    else hpair = hh;
                }
            }
        }
}

struct TailPtrs {
    const _Float16* Hs[9]; const _Float16* Hc[9]; const float* Cp[9];
    float* Co[9]; _Float16* Ho[9]; _Float16* So[9];
};

__global__ __launch_bounds__(256, 1) void tail_fused(
    TailPtrs tp,
    const _Float16* __restrict__ Wiou, const _Float16* __restrict__ Wf,
    const _Float16* __restrict__ XpI, const _Float16* __restrict__ XpF,
    float* __restrict__ fin, unsigned* __restrict__ bar)
{
    __shared__ __align__(16) _Float16 lA[2 * 192 * 32];   // 24 KB
    __shared__ __align__(16) _Float16 lB[2 * 256 * 32];   // 32 KB
    for (int idx = 0; idx < 9; ++idx) {
        int lvl = 8 - idx, n = 1 << lvl, gx0 = n - 1;
        int PT = (n + 63) >> 6, ntiles = PT * 16;
        if ((int)blockIdx.x < ntiles) {
            int p0 = (blockIdx.x % PT) * 64, c0 = (blockIdx.x / PT) * 64;
            tail_tile(tp.Hs[idx], tp.Hc[idx], Wiou, Wf, tp.Cp[idx], XpI, XpF,
                      tp.Co[idx], tp.Ho[idx], tp.So[idx], n, gx0,
                      (lvl == 0) ? fin : nullptr, p0, c0, lA, lB);
        }
        grid_barrier(bar, gridDim.x);
    }
}

// ---------------------------------------------------------------------------
extern "C" void kernel_launch(void* const* d_in, const int* in_sizes, int n_in,
                              void* d_out, int out_size, void* d_ws, size_t ws_size,
                              hipStream_t stream)
{
    const float* embs = (const float*)d_in[0];
    const float* Wix = (const float*)d_in[1];  const float* bix = (const float*)d_in[2];
    const float* Wih = (const float*)d_in[3];  const float* bih = (const float*)d_in[4];
    const float* Wfx = (const float*)d_in[5];  const float* bfx = (const float*)d_in[6];
    const float* Wfh = (const float*)d_in[7];  const float* bfh = (const float*)d_in[8];
    const float* Wox = (const float*)d_in[9];  const float* box_ = (const float*)d_in[10];
    const float* Woh = (const float*)d_in[11]; const float* boh = (const float*)d_in[12];
    const float* Wux = (const float*)d_in[13]; const float* bux = (const float*)d_in[14];
    const float* Wuh = (const float*)d_in[15]; const float* buh = (const float*)d_in[16];

    char* p = (char*)d_ws;
    auto carve = [&](size_t bytes) -> char* {
        char* r = p; p += (bytes + 255) & ~(size_t)255; return r;
    };
    unsigned*  bar    = (unsigned*)carve(256);
    _Float16* Wiou16 = (_Float16*)carve((size_t)3072 * 1024 * 2);   //   6.3 MB
    _Float16* Wfh16  = (_Float16*)carve((size_t)1024 * 1024 * 2);   //   2.1 MB
    _Float16* XpI    = (_Float16*)carve((size_t)8192 * 3072 * 2);   //  50.3 MB
    _Float16* XpF    = (_Float16*)carve((size_t)8192 * 1024 * 2);   //  16.8 MB
    _Float16* houpre = (_Float16*)carve((size_t)4096 * 3072 * 2);   //  25.2 MB
    _Float16* fpre   = (_Float16*)carve((size_t)8192 * 1024 * 2);   //  16.8 MB
    _Float16* H_A    = (_Float16*)carve((size_t)8192 * 1024 * 2);   //  16.8 MB
    _Float16* H_B    = (_Float16*)carve((size_t)4096 * 1024 * 2);   //   8.4 MB
    _Float16* HsumA  = (_Float16*)carve((size_t)4096 * 1024 * 2);   //   8.4 MB
    _Float16* HsumB  = (_Float16*)carve((size_t)4096 * 1024 * 2);   //   8.4 MB
    _Float16* Cleaf  = (_Float16*)carve((size_t)8192 * 1024 * 2);   //  16.8 MB
    float*    Cping  = (float*)carve((size_t)4096 * 1024 * 4);      //  16.8 MB
    float*    Cpong  = (float*)carve((size_t)2048 * 1024 * 4);      //   8.4 MB
    // total ~201 MB. Aliases (stream-ordered): x16/Bx live in fpre, dead
    // after leaf_fused; fpre first written at lvl12 gemm_level (later).
    _Float16* x16 = fpre;
    _Float16* Bx  = fpre + (size_t)16384 * XDIM;

    {   // pack (also zeroes grid-barrier state -> replay-safe)
        long long tot = 3072LL * 1024 + 1024LL * 1024 + 16384LL * XDIM + 4096LL * XDIM;
        pack_kernel<<<dim3((int)((tot + 255) / 256)), dim3(256), 0, stream>>>(
            embs, Wix, bix, Wih, bih, Wfx, bfx, Wfh, bfh,
            Wox, box_, Woh, boh, Wux, bux, Wuh, buh,
            Wiou16, Wfh16, x16, Bx, bar);
    }

    // XpI = x[0:8192] @ [Wix;Wox;Wux]^T (+bias), 8192x3072, K=320
    gemm_f16<128, 128, 64><<<dim3(64, 24), dim3(256), 0, stream>>>(
        x16, XDIM, Bx, XDIM, XpI, 3072, XDIM);
    // XpF = x[0:8192] @ Wfx^T (+bias), 8192x1024, K=320
    gemm_f16<128, 128, 64><<<dim3(64, 8), dim3(256), 0, stream>>>(
        x16, XDIM, Bx + (size_t)3072 * XDIM, XDIM, XpF, 1024, XDIM);
    // Leaf level fused GEMM+combine
    leaf_fused<<<dim3(128, 8), dim3(256), 0, stream>>>(x16, Bx, Cleaf, H_A, HsumA);

    const void* cprev = Cleaf;
    float* cbufs[2] = {Cping, Cpong};
    _Float16* hsums[2] = {HsumA, HsumB};
    int ci = 0, si = 0;
    _Float16* hcur = H_A;
    _Float16* hnext = H_B;

    // Big levels: lvl 12..9 (n = 4096..512)
    for (int lvl = 12; lvl >= 9; --lvl) {
        int n = 1 << lvl;
        int G1 = n / 128, G2 = 2 * n / 128;
        gemm_level<<<dim3(G1 * 24 + G2 * 8), dim3(256), 0, stream>>>(
            hsums[si], hcur, Wiou16, Wfh16, houpre, fpre, G1, G2);
        int blocks = ((n >> 1) * 128 + 255) / 256;
        if (lvl == 12)
            combine_level<true><<<dim3(blocks), dim3(256), 0, stream>>>(
                houpre, fpre, cprev, XpI, XpF, cbufs[ci], hnext, hsums[si ^ 1], n, n - 1);
        else
            combine_level<false><<<dim3(blocks), dim3(256), 0, stream>>>(
                houpre, fpre, cprev, XpI, XpF, cbufs[ci], hnext, hsums[si ^ 1], n, n - 1);
        cprev = cbufs[ci];
        ci ^= 1; si ^= 1;
        _Float16* tmp = hcur; hcur = hnext; hnext = tmp;
    }

    // Tail: lvl 8..0 (n = 256..1) in ONE persistent kernel
    TailPtrs tp;
    for (int lvl = 8; lvl >= 0; --lvl) {
        int idx = 8 - lvl;
        tp.Hs[idx] = hsums[si];
        tp.Hc[idx] = hcur;
        tp.Cp[idx] = (const float*)cprev;
        tp.Co[idx] = cbufs[ci];
        tp.Ho[idx] = hnext;
        tp.So[idx] = hsums[si ^ 1];
        cprev = cbufs[ci];
        ci ^= 1; si ^= 1;
        _Float16* tmp = hcur; hcur = hnext; hnext = tmp;
    }
    tail_fused<<<dim3(TAILNB), dim3(256), 0, stream>>>(
        tp, Wiou16, Wfh16, XpI, XpF, (float*)d_out, bar);
}

// Round 5
// 636.338 us; speedup vs baseline: 1.3152x; 1.3152x over previous
//
#include <hip/hip_runtime.h>
#include <hip/hip_bf16.h>

#define IN_DIM 300
#define XDIM   320      // x row padded: 300 vals + bias-one at col 300 + zeros
#define MEM    1024
#define NTREE  16383

typedef _Float16 half8 __attribute__((ext_vector_type(8)));
typedef float    f32x4 __attribute__((ext_vector_type(4)));

__device__ __forceinline__ float sigf(float x) { return 1.0f / (1.0f + __expf(-x)); }
__device__ __forceinline__ float tanhfast(float x) { return 2.0f / (1.0f + __expf(-2.0f * x)) - 1.0f; }

#define GLOAD_LDS16(g, l) \
    __builtin_amdgcn_global_load_lds((const __attribute__((address_space(1))) void*)(g), \
                                     (__attribute__((address_space(3))) void*)(l), 16, 0, 0)

// ---------------------------------------------------------------------------
// Pack (one-time): Wiou16 = [Wih;Woh;Wuh] (3072x1024 fp16), Wfh16 (1024x1024),
// x16 (16384x320: [x | 1.0 | 0...]), Bx (4096x320: [Wgx | bgx+bgh | 0...],
// rows g=i,o,u,f).
// ---------------------------------------------------------------------------
__global__ void pack_kernel(
    const float* __restrict__ embs,
    const float* __restrict__ Wix, const float* __restrict__ bix,
    const float* __restrict__ Wih, const float* __restrict__ bih,
    const float* __restrict__ Wfx, const float* __restrict__ bfx,
    const float* __restrict__ Wfh, const float* __restrict__ bfh,
    const float* __restrict__ Wox, const float* __restrict__ box_,
    const float* __restrict__ Woh, const float* __restrict__ boh,
    const float* __restrict__ Wux, const float* __restrict__ bux,
    const float* __restrict__ Wuh, const float* __restrict__ buh,
    _Float16* __restrict__ Wiou16, _Float16* __restrict__ Wfh16,
    _Float16* __restrict__ x16, _Float16* __restrict__ Bx)
{
    long long idx = (long long)blockIdx.x * blockDim.x + threadIdx.x;
    const long long n_wiou = 3072LL * 1024;
    const long long n_wfh  = 1024LL * 1024;
    const long long n_x    = 16384LL * XDIM;
    const long long n_bx   = 4096LL * XDIM;
    if (idx < n_wiou) {
        int m = (int)(idx >> 10), k = (int)(idx & 1023);
        int g = m >> 10, mm = m & 1023;
        const float* W = (g == 0) ? Wih : (g == 1) ? Woh : Wuh;
        Wiou16[idx] = (_Float16)W[(long long)mm * MEM + k];
        return;
    }
    idx -= n_wiou;
    if (idx < n_wfh) {
        Wfh16[idx] = (_Float16)Wfh[idx];
        return;
    }
    idx -= n_wfh;
    if (idx < n_x) {
        int node = (int)(idx / XDIM), j = (int)(idx % XDIM);
        float v = 0.f;
        if (node < NTREE) {
            if (j < IN_DIM) v = embs[(long long)node * IN_DIM + j];
            else if (j == IN_DIM) v = 1.0f;
        }
        x16[idx] = (_Float16)v;
        return;
    }
    idx -= n_x;
    if (idx < n_bx) {
        int r = (int)(idx / XDIM), j = (int)(idx % XDIM);
        int g = r >> 10, mm = r & 1023;
        const float* Wx = (g == 0) ? Wix : (g == 1) ? Wox : (g == 2) ? Wux : Wfx;
        const float* b1 = (g == 0) ? bix : (g == 1) ? box_ : (g == 2) ? bux : bfx;
        const float* b2 = (g == 0) ? bih : (g == 1) ? boh : (g == 2) ? buh : bfh;
        float v = 0.f;
        if (j < IN_DIM) v = Wx[(long long)mm * IN_DIM + j];
        else if (j == IN_DIM) v = b1[mm] + b2[mm];
        Bx[idx] = (_Float16)v;
    }
}

// ---------------------------------------------------------------------------
// GEMM tile core: C(BMxBN) = A(BMxK) * B(BNxK)^T. fp16 in / f32 MFMA / fp16
// out. 4 waves (2x2). Single-buffered LDS, m97 2-barrier structure. BK=64
// XOR swizzle (rule 21: linear LDS dest + inverse-swizzled global source +
// swizzled ds_read): SQ_LDS_BANK_CONFLICT = 0 (verified r3).
// ---------------------------------------------------------------------------
template<int BM, int BN, int BK>
__device__ __forceinline__ void gemm_tile(
    const _Float16* __restrict__ A, int lda,
    const _Float16* __restrict__ B, int ldb,
    _Float16* __restrict__ C, int ldc, int K,
    _Float16* ldsA, _Float16* ldsB)
{
    constexpr int FM = BM / 32, FN = BN / 32;
    constexpr int CPR = BK / 8, SWM = CPR - 1;
    constexpr int ACH = BM * BK / 2048, BCH = BN * BK / 2048;

    int tid = threadIdx.x, wave = tid >> 6, lane = tid & 63;
    int wr = (wave >> 1) * (BM / 2), wc = (wave & 1) * (BN / 2);
    int kq = (lane >> 4) * 8, rs = lane & 15;
    f32x4 acc[FM][FN] = {};

    for (int k0 = 0; k0 < K; k0 += BK) {
#pragma unroll
        for (int j = 0; j < ACH; ++j) {
            int c = j * 256 + tid;
            int row = c / CPR;
            int s = (c ^ row) & SWM;
            GLOAD_LDS16(A + (long long)row * lda + k0 + s * 8,
                        &ldsA[(j * 256 + wave * 64) * 8]);
        }
#pragma unroll
        for (int j = 0; j < BCH; ++j) {
            int c = j * 256 + tid;
            int row = c / CPR;
            int s = (c ^ row) & SWM;
            GLOAD_LDS16(B + (long long)row * ldb + k0 + s * 8,
                        &ldsB[(j * 256 + wave * 64) * 8]);
        }
        __syncthreads();
#pragma unroll
        for (int kk = 0; kk < BK; kk += 32) {
            half8 a[FM], b[FN];
#pragma unroll
            for (int i = 0; i < FM; ++i) {
                int r = wr + i * 16 + rs;
                int s = ((kk + kq) >> 3) ^ (r & SWM);
                a[i] = *(const half8*)&ldsA[r * BK + s * 8];
            }
#pragma unroll
            for (int i = 0; i < FN; ++i) {
                int r = wc + i * 16 + rs;
                int s = ((kk + kq) >> 3) ^ (r & SWM);
                b[i] = *(const half8*)&ldsB[r * BK + s * 8];
            }
#pragma unroll
            for (int mi = 0; mi < FM; ++mi)
#pragma unroll
                for (int ni = 0; ni < FN; ++ni)
                    acc[mi][ni] = __builtin_amdgcn_mfma_f32_16x16x32_f16(a[mi], b[ni], acc[mi][ni], 0, 0, 0);
        }
        __syncthreads();
    }
    // C/D layout: col = lane&15, row = (lane>>4)*4 + reg  [m89-verified]
    int crb = wr + (lane >> 4) * 4, ccb = wc + rs;
#pragma unroll
    for (int mi = 0; mi < FM; ++mi)
#pragma unroll
        for (int i = 0; i < 4; ++i) {
            long long r = crb + mi * 16 + i;
#pragma unroll
            for (int ni = 0; ni < FN; ++ni)
                C[r * ldc + ccb + ni * 16] = (_Float16)acc[mi][ni][i];
        }
}

template<int BM, int BN, int BK>
__global__ __launch_bounds__(256) void gemm_f16(
    const _Float16* __restrict__ A, int lda,
    const _Float16* __restrict__ B, int ldb,
    _Float16* __restrict__ C, int ldc, int K)
{
    __shared__ __align__(16) _Float16 ldsA[BM * BK];
    __shared__ __align__(16) _Float16 ldsB[BN * BK];
    gemm_tile<BM, BN, BK>(A + (long long)blockIdx.x * BM * lda, lda,
                          B + (long long)blockIdx.y * BN * ldb, ldb,
                          C + (long long)blockIdx.x * BM * ldc + (long long)blockIdx.y * BN,
                          ldc, K, ldsA, ldsB);
}

// Fused per-level GEMM (big levels n>=512): part1 = hsum @ Wiou^T (n x 3072),
// part2 = H @ Wfh^T (2n x 1024). Both K=1024. 32 KB LDS.
__global__ __launch_bounds__(256) void gemm_level(
    const _Float16* __restrict__ Hsum, const _Float16* __restrict__ Hc,
    const _Float16* __restrict__ Wiou, const _Float16* __restrict__ Wf,
    _Float16* __restrict__ houpre, _Float16* __restrict__ fpre,
    int G1, int G2)
{
    __shared__ __align__(16) _Float16 ldsA[128 * 64];
    __shared__ __align__(16) _Float16 ldsB[128 * 64];
    int bx = blockIdx.x;
    if (bx < G1 * 24) {
        int nb = bx / G1, mb = bx % G1;
        gemm_tile<128, 128, 64>(Hsum + (long long)mb * 128 * 1024, 1024,
                                Wiou + (long long)nb * 128 * 1024, 1024,
                                houpre + (long long)mb * 128 * 3072 + nb * 128, 3072,
                                1024, ldsA, ldsB);
    } else {
        int b2 = bx - G1 * 24;
        int nb = b2 / G2, mb = b2 % G2;
        gemm_tile<128, 128, 64>(Hc + (long long)mb * 128 * 1024, 1024,
                                Wf + (long long)nb * 128 * 1024, 1024,
                                fpre + (long long)mb * 128 * 1024 + nb * 128, 1024,
                                1024, ldsA, ldsB);
    }
}

// ---------------------------------------------------------------------------
// Leaf fused GEMM+combine: tile 64 leaves x 128 cols, 3 gate accumulators
// (i,o,u), K=320, single-buffered (28 KB LDS). Writes cleaf/h/hsum.
// ---------------------------------------------------------------------------
__global__ __launch_bounds__(256) void leaf_fused(
    const _Float16* __restrict__ x16, const _Float16* __restrict__ Bx,
    _Float16* __restrict__ cleaf, _Float16* __restrict__ hleaf,
    _Float16* __restrict__ hsum)
{
    constexpr int BK = 32, CPR = 4, SWM = 3;
    __shared__ __align__(16) _Float16 lA[64 * BK];
    __shared__ __align__(16) _Float16 lB[384 * BK];
    int tid = threadIdx.x, wave = tid >> 6, lane = tid & 63;
    int kq = (lane >> 4) * 8, rs = lane & 15;
    int wr = (wave >> 1) * 32, wc = (wave & 1) * 64;
    int m0 = blockIdx.x * 64, c0 = blockIdx.y * 128;
    const _Float16* A = x16 + (size_t)(8191 + m0) * XDIM;

    f32x4 acc[3][2][4] = {};
    for (int t = 0; t < 10; ++t) {     // K = 320
        int k0 = t * BK;
        {   // A: 256 chunks, 1/thread
            int c = tid, row = c / CPR, s = (c ^ row) & SWM;
            GLOAD_LDS16(A + (long long)row * XDIM + k0 + s * 8, &lA[(wave * 64) * 8]);
        }
#pragma unroll
        for (int j = 0; j < 6; ++j) {   // B: 1536 chunks (3 gate tiles x 128)
            int c = j * 256 + tid;
            int row = c / CPR, s = (c ^ row) & SWM;
            int g = row >> 7, rr = row & 127;
            GLOAD_LDS16(Bx + (long long)(g * 1024 + c0 + rr) * XDIM + k0 + s * 8,
                        &lB[(j * 256 + wave * 64) * 8]);
        }
        __syncthreads();
        half8 a[2], b[3][4];
#pragma unroll
        for (int mi = 0; mi < 2; ++mi) {
            int r = wr + mi * 16 + rs;
            int s = (kq >> 3) ^ (r & SWM);
            a[mi] = *(const half8*)&lA[r * BK + s * 8];
        }
#pragma unroll
        for (int g = 0; g < 3; ++g)
#pragma unroll
            for (int nj = 0; nj < 4; ++nj) {
                int r = g * 128 + wc + nj * 16 + rs;
                int s = (kq >> 3) ^ (r & SWM);
                b[g][nj] = *(const half8*)&lB[r * BK + s * 8];
            }
#pragma unroll
        for (int g = 0; g < 3; ++g)
#pragma unroll
            for (int mi = 0; mi < 2; ++mi)
#pragma unroll
                for (int nj = 0; nj < 4; ++nj)
                    acc[g][mi][nj] = __builtin_amdgcn_mfma_f32_16x16x32_f16(a[mi], b[g][nj], acc[g][mi][nj], 0, 0, 0);
        __syncthreads();
    }
    int lrb = wr + (lane >> 4) * 4;
#pragma unroll
    for (int mi = 0; mi < 2; ++mi)
#pragma unroll
        for (int nj = 0; nj < 4; ++nj) {
            int col = c0 + wc + nj * 16 + rs;
            float hpair = 0.f;
#pragma unroll
            for (int i = 0; i < 4; ++i) {
                long long l = m0 + lrb + mi * 16 + i;
                float cc = sigf(acc[0][mi][nj][i]) * tanhfast(acc[2][mi][nj][i]);
                float hh = sigf(acc[1][mi][nj][i]) * tanhfast(cc);
                cleaf[l * 1024 + col] = (_Float16)cc;
                hleaf[l * 1024 + col] = (_Float16)hh;
                if (i & 1) hsum[(l >> 1) * 1024 + col] = (_Float16)(hpair + hh);
                else hpair = hh;
            }
        }
}

// ---------------------------------------------------------------------------
// Internal-level combine (big levels): gates from houpre + XpI, f per child
// from fpre + XpF(parent), c = i*u + f0*c0 + f1*c1, h = o*tanh(c).
// ---------------------------------------------------------------------------
template<bool C16>
__global__ void combine_level(
    const _Float16* __restrict__ houpre, const _Float16* __restrict__ fpre,
    const void* __restrict__ cprevp,
    const _Float16* __restrict__ XpI, const _Float16* __restrict__ XpF,
    float* __restrict__ cout, _Float16* __restrict__ hout, _Float16* __restrict__ hsum,
    int n, int gx0)
{
    int idx = blockIdx.x * blockDim.x + threadIdx.x;
    int npairs = n >> 1;
    if (idx >= npairs * 128) return;
    int r = idx >> 7, m8 = (idx & 127) * 8;
    float hs[8];
#pragma unroll
    for (int j = 0; j < 8; ++j) hs[j] = 0.f;
    for (int t = 0; t < 2; ++t) {
        int p = 2 * r + t;
        long long node = gx0 + p;
        half8 phi = *(const half8*)&houpre[(long long)p * 3072 + m8];
        half8 pho = *(const half8*)&houpre[(long long)p * 3072 + 1024 + m8];
        half8 phu = *(const half8*)&houpre[(long long)p * 3072 + 2048 + m8];
        half8 pxi = *(const half8*)&XpI[node * 3072 + m8];
        half8 pxo = *(const half8*)&XpI[node * 3072 + 1024 + m8];
        half8 pxu = *(const half8*)&XpI[node * 3072 + 2048 + m8];
        half8 pf0 = *(const half8*)&fpre[(long long)(2 * p) * 1024 + m8];
        half8 pf1 = *(const half8*)&fpre[(long long)(2 * p + 1) * 1024 + m8];
        half8 pxf = *(const half8*)&XpF[node * 1024 + m8];
        float c0[8], c1[8];
        if (C16) {
            const _Float16* cp = (const _Float16*)cprevp;
            half8 a = *(const half8*)&cp[(long long)(2 * p) * 1024 + m8];
            half8 b = *(const half8*)&cp[(long long)(2 * p + 1) * 1024 + m8];
#pragma unroll
            for (int j = 0; j < 8; ++j) { c0[j] = (float)a[j]; c1[j] = (float)b[j]; }
        } else {
            const float* cp = (const float*)cprevp;
            f32x4 a0 = *(const f32x4*)&cp[(long long)(2 * p) * 1024 + m8];
            f32x4 a1 = *(const f32x4*)&cp[(long long)(2 * p) * 1024 + m8 + 4];
            f32x4 b0 = *(const f32x4*)&cp[(long long)(2 * p + 1) * 1024 + m8];
            f32x4 b1 = *(const f32x4*)&cp[(long long)(2 * p + 1) * 1024 + m8 + 4];
#pragma unroll
            for (int j = 0; j < 4; ++j) { c0[j] = a0[j]; c0[j + 4] = a1[j]; c1[j] = b0[j]; c1[j + 4] = b1[j]; }
        }
        float cw[8], hw[8];
#pragma unroll
        for (int j = 0; j < 8; ++j) {
            float i  = sigf((float)phi[j] + (float)pxi[j]);
            float o  = sigf((float)pho[j] + (float)pxo[j]);
            float u  = tanhfast((float)phu[j] + (float)pxu[j]);
            float f0 = sigf((float)pf0[j] + (float)pxf[j]);
            float f1 = sigf((float)pf1[j] + (float)pxf[j]);
            float c = i * u + f0 * c0[j] + f1 * c1[j];
            float h = o * tanhfast(c);
            cw[j] = c; hw[j] = h; hs[j] += h;
        }
        f32x4 v0 = {cw[0], cw[1], cw[2], cw[3]}, v1 = {cw[4], cw[5], cw[6], cw[7]};
        *(f32x4*)&cout[(long long)p * 1024 + m8] = v0;
        *(f32x4*)&cout[(long long)p * 1024 + m8 + 4] = v1;
        half8 hv;
#pragma unroll
        for (int j = 0; j < 8; ++j) hv[j] = (_Float16)hw[j];
        *(half8*)&hout[(long long)p * 1024 + m8] = hv;
    }
    half8 sv;
#pragma unroll
    for (int j = 0; j < 8; ++j) sv[j] = (_Float16)hs[j];
    *(half8*)&hsum[(long long)r * 1024 + m8] = sv;
}

// ---------------------------------------------------------------------------
// Fused GEMM+combine for small levels (n <= 256), ONE LAUNCH PER LEVEL.
// Tile 64 parents x 64 cols, 5 MFMA groups: i,o,u (A=hsum), f-even (A=h[2p]),
// f-odd (A=h[2p+1]). K=1024, BK=32, double-buffered with COUNTED vmcnt
// (T4/m218): raw s_barrier keeps next tile's 7 global_load_lds in flight
// across the barrier; vmcnt(7) waits only for the CURRENT tile's loads.
// ---------------------------------------------------------------------------
__global__ __launch_bounds__(256) void level_fused(
    const _Float16* __restrict__ Hs, const _Float16* __restrict__ Hc,
    const _Float16* __restrict__ Wiou, const _Float16* __restrict__ Wf,
    const float* __restrict__ cprev,
    const _Float16* __restrict__ XpI, const _Float16* __restrict__ XpF,
    float* __restrict__ cout, _Float16* __restrict__ hout,
    _Float16* __restrict__ hsumout, int n, int gx0, float* __restrict__ fin)
{
    constexpr int BK = 32, CPR = 4, SWM = 3;
    __shared__ __align__(16) _Float16 lA[2 * 192 * BK];   // 24 KB: hsum|heven|hodd
    __shared__ __align__(16) _Float16 lB[2 * 256 * BK];   // 32 KB: i|o|u|f (64 rows)
    int tid = threadIdx.x, wave = tid >> 6, lane = tid & 63;
    int kq = (lane >> 4) * 8, rs = lane & 15;
    int wr = (wave >> 1) * 32, wc = (wave & 1) * 32;
    int PT = (n + 63) >> 6;
    int p0 = ((int)blockIdx.x % PT) * 64, c0 = ((int)blockIdx.x / PT) * 64;

    // 7 global_load_lds per thread per stage (3 A + 4 B) -> vmcnt counts 7/wave
    auto stage = [&](int buf, int k0) {
#pragma unroll
        for (int j = 0; j < 3; ++j) {          // A: 768 chunks (hsum|heven|hodd)
            int c = j * 256 + tid;
            int row = c / CPR, s = (c ^ row) & SWM;
            int ta = row >> 6, rr = row & 63;
            const _Float16* src = (ta == 0) ? Hs : Hc;
            long long grow = (ta == 0) ? (long long)(p0 + rr)
                                       : (2LL * (p0 + rr) + (ta - 1));
            GLOAD_LDS16(src + grow * 1024 + k0 + s * 8,
                        &lA[buf * 192 * BK + (j * 256 + wave * 64) * 8]);
        }
#pragma unroll
        for (int j = 0; j < 4; ++j) {          // B: 1024 chunks (i|o|u|f, 64 rows)
            int c = j * 256 + tid;
            int row = c / CPR, s = (c ^ row) & SWM;
            int tb = row >> 6, rr = row & 63;
            const _Float16* src = (tb < 3) ? Wiou : Wf;
            long long grow = (tb < 3) ? (long long)(tb * 1024 + c0 + rr)
                                      : (long long)(c0 + rr);
            GLOAD_LDS16(src + grow * 1024 + k0 + s * 8,
                        &lB[buf * 256 * BK + (j * 256 + wave * 64) * 8]);
        }
    };
    f32x4 acc[5][2][2] = {};
    stage(0, 0);
    for (int t = 0; t < 32; ++t) {             // K = 1024
        if (t + 1 < 32) {
            stage((t + 1) & 1, (t + 1) * BK);          // issue next (7 in flight)
            asm volatile("s_waitcnt vmcnt(7)" ::: "memory");   // current landed
        } else {
            asm volatile("s_waitcnt vmcnt(0)" ::: "memory");
        }
        asm volatile("s_barrier" ::: "memory");        // everyone's current landed
        const _Float16* bA = lA + (t & 1) * 192 * BK;
        const _Float16* bB = lB + (t & 1) * 256 * BK;
        half8 a[3][2], b[4][2];
#pragma unroll
        for (int ta = 0; ta < 3; ++ta)
#pragma unroll
            for (int mi = 0; mi < 2; ++mi) {
                int r = ta * 64 + wr + mi * 16 + rs;
                int s = (kq >> 3) ^ (r & SWM);
                a[ta][mi] = *(const half8*)&bA[r * BK + s * 8];
            }
#pragma unroll
        for (int tb = 0; tb < 4; ++tb)
#pragma unroll
            for (int nj = 0; nj < 2; ++nj) {
                int r = tb * 64 + wc + nj * 16 + rs;
                int s = (kq >> 3) ^ (r & SWM);
                b[tb][nj] = *(const half8*)&bB[r * BK + s * 8];
            }
#pragma unroll
        for (int mi = 0; mi < 2; ++mi)
#pragma unroll
            for (int nj = 0; nj < 2; ++nj) {
                acc[0][mi][nj] = __builtin_amdgcn_mfma_f32_16x16x32_f16(a[0][mi], b[0][nj], acc[0][mi][nj], 0, 0, 0);
                acc[1][mi][nj] = __builtin_amdgcn_mfma_f32_16x16x32_f16(a[0][mi], b[1][nj], acc[1][mi][nj], 0, 0, 0);
                acc[2][mi][nj] = __builtin_amdgcn_mfma_f32_16x16x32_f16(a[0][mi], b[2][nj], acc[2][mi][nj], 0, 0, 0);
                acc[3][mi][nj] = __builtin_amdgcn_mfma_f32_16x16x32_f16(a[1][mi], b[3][nj], acc[3][mi][nj], 0, 0, 0);
                acc[4][mi][nj] = __builtin_amdgcn_mfma_f32_16x16x32_f16(a[2][mi], b[3][nj], acc[4][mi][nj], 0, 0, 0);
            }
        // ds_read results all consumed by MFMAs above (compiler lgkmcnt),
        // so buffer (t&1) is free to overwrite after this barrier.
        asm volatile("s_barrier" ::: "memory");
    }
    int lrb = wr + (lane >> 4) * 4;
#pragma unroll
    for (int mi = 0; mi < 2; ++mi)
#pragma unroll
        for (int nj = 0; nj < 2; ++nj) {
            int col = c0 + wc + nj * 16 + rs;
            float hpair = 0.f;
#pragma unroll
            for (int i = 0; i < 4; ++i) {
                int p = p0 + lrb + mi * 16 + i;
                if (p >= n) continue;
                long long node = gx0 + p;
                float ip = acc[0][mi][nj][i] + (float)XpI[node * 3072 + col];
                float op = acc[1][mi][nj][i] + (float)XpI[node * 3072 + 1024 + col];
                float up = acc[2][mi][nj][i] + (float)XpI[node * 3072 + 2048 + col];
                float xf = (float)XpF[node * 1024 + col];
                float f0 = sigf(acc[3][mi][nj][i] + xf);
                float f1 = sigf(acc[4][mi][nj][i] + xf);
                float cc = sigf(ip) * tanhfast(up)
                         + f0 * cprev[(long long)(2 * p) * 1024 + col]
                         + f1 * cprev[(long long)(2 * p + 1) * 1024 + col];
                float hh = sigf(op) * tanhfast(cc);
                if (fin) {
                    if (p == 0) { fin[col] = cc; fin[1024 + col] = hh; }
                } else {
                    cout[(long long)p * 1024 + col] = cc;
                    hout[(long long)p * 1024 + col] = (_Float16)hh;
                    if (i & 1) hsumout[((long long)(p >> 1)) * 1024 + col] = (_Float16)(hpair + hh);
                    else hpair = hh;
                }
            }
        }
}

// ---------------------------------------------------------------------------
extern "C" void kernel_launch(void* const* d_in, const int* in_sizes, int n_in,
                              void* d_out, int out_size, void* d_ws, size_t ws_size,
                              hipStream_t stream)
{
    const float* embs = (const float*)d_in[0];
    const float* Wix = (const float*)d_in[1];  const float* bix = (const float*)d_in[2];
    const float* Wih = (const float*)d_in[3];  const float* bih = (const float*)d_in[4];
    const float* Wfx = (const float*)d_in[5];  const float* bfx = (const float*)d_in[6];
    const float* Wfh = (const float*)d_in[7];  const float* bfh = (const float*)d_in[8];
    const float* Wox = (const float*)d_in[9];  const float* box_ = (const float*)d_in[10];
    const float* Woh = (const float*)d_in[11]; const float* boh = (const float*)d_in[12];
    const float* Wux = (const float*)d_in[13]; const float* bux = (const float*)d_in[14];
    const float* Wuh = (const float*)d_in[15]; const float* buh = (const float*)d_in[16];

    char* p = (char*)d_ws;
    auto carve = [&](size_t bytes) -> char* {
        char* r = p; p += (bytes + 255) & ~(size_t)255; return r;
    };
    _Float16* Wiou16 = (_Float16*)carve((size_t)3072 * 1024 * 2);   //   6.3 MB
    _Float16* Wfh16  = (_Float16*)carve((size_t)1024 * 1024 * 2);   //   2.1 MB
    _Float16* XpI    = (_Float16*)carve((size_t)8192 * 3072 * 2);   //  50.3 MB
    _Float16* XpF    = (_Float16*)carve((size_t)8192 * 1024 * 2);   //  16.8 MB
    _Float16* houpre = (_Float16*)carve((size_t)4096 * 3072 * 2);   //  25.2 MB
    _Float16* fpre   = (_Float16*)carve((size_t)8192 * 1024 * 2);   //  16.8 MB
    _Float16* H_A    = (_Float16*)carve((size_t)8192 * 1024 * 2);   //  16.8 MB
    _Float16* H_B    = (_Float16*)carve((size_t)4096 * 1024 * 2);   //   8.4 MB
    _Float16* HsumA  = (_Float16*)carve((size_t)4096 * 1024 * 2);   //   8.4 MB
    _Float16* HsumB  = (_Float16*)carve((size_t)4096 * 1024 * 2);   //   8.4 MB
    _Float16* Cleaf  = (_Float16*)carve((size_t)8192 * 1024 * 2);   //  16.8 MB
    float*    Cping  = (float*)carve((size_t)4096 * 1024 * 4);      //  16.8 MB
    float*    Cpong  = (float*)carve((size_t)2048 * 1024 * 4);      //   8.4 MB
    // total ~201 MB. Aliases (stream-ordered): x16/Bx live in fpre, dead
    // after leaf_fused; fpre first written at lvl12 gemm_level (later).
    _Float16* x16 = fpre;
    _Float16* Bx  = fpre + (size_t)16384 * XDIM;

    {   // pack
        long long tot = 3072LL * 1024 + 1024LL * 1024 + 16384LL * XDIM + 4096LL * XDIM;
        pack_kernel<<<dim3((int)((tot + 255) / 256)), dim3(256), 0, stream>>>(
            embs, Wix, bix, Wih, bih, Wfx, bfx, Wfh, bfh,
            Wox, box_, Woh, boh, Wux, bux, Wuh, buh,
            Wiou16, Wfh16, x16, Bx);
    }

    // XpI = x[0:8192] @ [Wix;Wox;Wux]^T (+bias), 8192x3072, K=320
    gemm_f16<128, 128, 64><<<dim3(64, 24), dim3(256), 0, stream>>>(
        x16, XDIM, Bx, XDIM, XpI, 3072, XDIM);
    // XpF = x[0:8192] @ Wfx^T (+bias), 8192x1024, K=320
    gemm_f16<128, 128, 64><<<dim3(64, 8), dim3(256), 0, stream>>>(
        x16, XDIM, Bx + (size_t)3072 * XDIM, XDIM, XpF, 1024, XDIM);
    // Leaf level fused GEMM+combine
    leaf_fused<<<dim3(128, 8), dim3(256), 0, stream>>>(x16, Bx, Cleaf, H_A, HsumA);

    const void* cprev = Cleaf;
    float* cbufs[2] = {Cping, Cpong};
    _Float16* hsums[2] = {HsumA, HsumB};
    int ci = 0, si = 0;
    _Float16* hcur = H_A;
    _Float16* hnext = H_B;

    // Big levels: lvl 12..9 (n = 4096..512)
    for (int lvl = 12; lvl >= 9; --lvl) {
        int n = 1 << lvl;
        int G1 = n / 128, G2 = 2 * n / 128;
        gemm_level<<<dim3(G1 * 24 + G2 * 8), dim3(256), 0, stream>>>(
            hsums[si], hcur, Wiou16, Wfh16, houpre, fpre, G1, G2);
        int blocks = ((n >> 1) * 128 + 255) / 256;
        if (lvl == 12)
            combine_level<true><<<dim3(blocks), dim3(256), 0, stream>>>(
                houpre, fpre, cprev, XpI, XpF, cbufs[ci], hnext, hsums[si ^ 1], n, n - 1);
        else
            combine_level<false><<<dim3(blocks), dim3(256), 0, stream>>>(
                houpre, fpre, cprev, XpI, XpF, cbufs[ci], hnext, hsums[si ^ 1], n, n - 1);
        cprev = cbufs[ci];
        ci ^= 1; si ^= 1;
        _Float16* tmp = hcur; hcur = hnext; hnext = tmp;
    }

    // Tail: lvl 8..0 (n = 256..1), one fused launch per level
    for (int lvl = 8; lvl >= 0; --lvl) {
        int n = 1 << lvl;
        int PT = (n + 63) >> 6;
        level_fused<<<dim3(PT * 16), dim3(256), 0, stream>>>(
            hsums[si], hcur, Wiou16, Wfh16, (const float*)cprev, XpI, XpF,
            cbufs[ci], hnext, hsums[si ^ 1], n, n - 1,
            (lvl == 0) ? (float*)d_out : nullptr);
        cprev = cbufs[ci];
        ci ^= 1; si ^= 1;
        _Float16* tmp = hcur; hcur = hnext; hnext = tmp;
    }
}

// Round 6
// 449.338 us; speedup vs baseline: 1.8626x; 1.4162x over previous
//
#include <hip/hip_runtime.h>
#include <hip/hip_bf16.h>

#define IN_DIM 300
#define XDIM   320      // x row padded: 300 vals + bias-one at col 300 + zeros
#define MEM    1024
#define NTREE  16383

typedef _Float16 half8 __attribute__((ext_vector_type(8)));
typedef float    f32x4 __attribute__((ext_vector_type(4)));

__device__ __forceinline__ float sigf(float x) { return 1.0f / (1.0f + __expf(-x)); }
__device__ __forceinline__ float tanhfast(float x) { return 2.0f / (1.0f + __expf(-2.0f * x)) - 1.0f; }

#define GLOAD_LDS16(g, l) \
    __builtin_amdgcn_global_load_lds((const __attribute__((address_space(1))) void*)(g), \
                                     (__attribute__((address_space(3))) void*)(l), 16, 0, 0)

// ---------------------------------------------------------------------------
// Pack (one-time): Wiou16 = [Wih;Woh;Wuh] (3072x1024 fp16), Wfh16 (1024x1024),
// x16 (16384x320: [x | 1.0 | 0...]), Bx (4096x320: [Wgx | bgx+bgh | 0...],
// rows g=i,o,u,f).
// ---------------------------------------------------------------------------
__global__ void pack_kernel(
    const float* __restrict__ embs,
    const float* __restrict__ Wix, const float* __restrict__ bix,
    const float* __restrict__ Wih, const float* __restrict__ bih,
    const float* __restrict__ Wfx, const float* __restrict__ bfx,
    const float* __restrict__ Wfh, const float* __restrict__ bfh,
    const float* __restrict__ Wox, const float* __restrict__ box_,
    const float* __restrict__ Woh, const float* __restrict__ boh,
    const float* __restrict__ Wux, const float* __restrict__ bux,
    const float* __restrict__ Wuh, const float* __restrict__ buh,
    _Float16* __restrict__ Wiou16, _Float16* __restrict__ Wfh16,
    _Float16* __restrict__ x16, _Float16* __restrict__ Bx)
{
    long long idx = (long long)blockIdx.x * blockDim.x + threadIdx.x;
    const long long n_wiou = 3072LL * 1024;
    const long long n_wfh  = 1024LL * 1024;
    const long long n_x    = 16384LL * XDIM;
    const long long n_bx   = 4096LL * XDIM;
    if (idx < n_wiou) {
        int m = (int)(idx >> 10), k = (int)(idx & 1023);
        int g = m >> 10, mm = m & 1023;
        const float* W = (g == 0) ? Wih : (g == 1) ? Woh : Wuh;
        Wiou16[idx] = (_Float16)W[(long long)mm * MEM + k];
        return;
    }
    idx -= n_wiou;
    if (idx < n_wfh) {
        Wfh16[idx] = (_Float16)Wfh[idx];
        return;
    }
    idx -= n_wfh;
    if (idx < n_x) {
        int node = (int)(idx / XDIM), j = (int)(idx % XDIM);
        float v = 0.f;
        if (node < NTREE) {
            if (j < IN_DIM) v = embs[(long long)node * IN_DIM + j];
            else if (j == IN_DIM) v = 1.0f;
        }
        x16[idx] = (_Float16)v;
        return;
    }
    idx -= n_x;
    if (idx < n_bx) {
        int r = (int)(idx / XDIM), j = (int)(idx % XDIM);
        int g = r >> 10, mm = r & 1023;
        const float* Wx = (g == 0) ? Wix : (g == 1) ? Wox : (g == 2) ? Wux : Wfx;
        const float* b1 = (g == 0) ? bix : (g == 1) ? box_ : (g == 2) ? bux : bfx;
        const float* b2 = (g == 0) ? bih : (g == 1) ? boh : (g == 2) ? buh : bfh;
        float v = 0.f;
        if (j < IN_DIM) v = Wx[(long long)mm * IN_DIM + j];
        else if (j == IN_DIM) v = b1[mm] + b2[mm];
        Bx[idx] = (_Float16)v;
    }
}

// ---------------------------------------------------------------------------
// GEMM tile core: C(BMxBN) = A(BMxK) * B(BNxK)^T. fp16 in / f32 MFMA / fp16
// out. 4 waves (2x2). Single-buffered LDS, m97 2-barrier structure (proven
// fastest at 2-phase: r2 63.7us vs r3-dbuf 79.6 / r5-BK64 69.3). XOR swizzle
// slot arithmetic kept (rule-21-compliant); residual 4-way conflicts at BK=32
// are hidden by the 2-phase structure (m252 regime gate).
// ---------------------------------------------------------------------------
template<int BM, int BN, int BK>
__device__ __forceinline__ void gemm_tile(
    const _Float16* __restrict__ A, int lda,
    const _Float16* __restrict__ B, int ldb,
    _Float16* __restrict__ C, int ldc, int K,
    _Float16* ldsA, _Float16* ldsB)
{
    constexpr int FM = BM / 32, FN = BN / 32;
    constexpr int CPR = BK / 8, SWM = CPR - 1;
    constexpr int ACH = BM * BK / 2048, BCH = BN * BK / 2048;

    int tid = threadIdx.x, wave = tid >> 6, lane = tid & 63;
    int wr = (wave >> 1) * (BM / 2), wc = (wave & 1) * (BN / 2);
    int kq = (lane >> 4) * 8, rs = lane & 15;
    f32x4 acc[FM][FN] = {};

    for (int k0 = 0; k0 < K; k0 += BK) {
#pragma unroll
        for (int j = 0; j < ACH; ++j) {
            int c = j * 256 + tid;
            int row = c / CPR;
            int s = (c ^ row) & SWM;
            GLOAD_LDS16(A + (long long)row * lda + k0 + s * 8,
                        &ldsA[(j * 256 + wave * 64) * 8]);
        }
#pragma unroll
        for (int j = 0; j < BCH; ++j) {
            int c = j * 256 + tid;
            int row = c / CPR;
            int s = (c ^ row) & SWM;
            GLOAD_LDS16(B + (long long)row * ldb + k0 + s * 8,
                        &ldsB[(j * 256 + wave * 64) * 8]);
        }
        __syncthreads();
#pragma unroll
        for (int kk = 0; kk < BK; kk += 32) {
            half8 a[FM], b[FN];
#pragma unroll
            for (int i = 0; i < FM; ++i) {
                int r = wr + i * 16 + rs;
                int s = ((kk + kq) >> 3) ^ (r & SWM);
                a[i] = *(const half8*)&ldsA[r * BK + s * 8];
            }
#pragma unroll
            for (int i = 0; i < FN; ++i) {
                int r = wc + i * 16 + rs;
                int s = ((kk + kq) >> 3) ^ (r & SWM);
                b[i] = *(const half8*)&ldsB[r * BK + s * 8];
            }
#pragma unroll
            for (int mi = 0; mi < FM; ++mi)
#pragma unroll
                for (int ni = 0; ni < FN; ++ni)
                    acc[mi][ni] = __builtin_amdgcn_mfma_f32_16x16x32_f16(a[mi], b[ni], acc[mi][ni], 0, 0, 0);
        }
        __syncthreads();
    }
    // C/D layout: col = lane&15, row = (lane>>4)*4 + reg  [m89-verified]
    int crb = wr + (lane >> 4) * 4, ccb = wc + rs;
#pragma unroll
    for (int mi = 0; mi < FM; ++mi)
#pragma unroll
        for (int i = 0; i < 4; ++i) {
            long long r = crb + mi * 16 + i;
#pragma unroll
            for (int ni = 0; ni < FN; ++ni)
                C[r * ldc + ccb + ni * 16] = (_Float16)acc[mi][ni][i];
        }
}

template<int BM, int BN, int BK>
__global__ __launch_bounds__(256) void gemm_f16(
    const _Float16* __restrict__ A, int lda,
    const _Float16* __restrict__ B, int ldb,
    _Float16* __restrict__ C, int ldc, int K)
{
    __shared__ __align__(16) _Float16 ldsA[BM * BK];
    __shared__ __align__(16) _Float16 ldsB[BN * BK];
    gemm_tile<BM, BN, BK>(A + (long long)blockIdx.x * BM * lda, lda,
                          B + (long long)blockIdx.y * BN * ldb, ldb,
                          C + (long long)blockIdx.x * BM * ldc + (long long)blockIdx.y * BN,
                          ldc, K, ldsA, ldsB);
}

// Fused per-level GEMM: part1 = hsum @ Wiou^T (n x 3072), part2 = H @ Wfh^T
// (2n x 1024). Both K=1024. BK=32 for big levels (16KB LDS, occupancy-best);
// BK=128 for small levels (8 K-steps: each serial step at tiny grids costs
// ~1 exposed load latency -> step COUNT dominates; r5's BK=32 tail was
// ~36us/level vs r2's BK=128 ~8us/level).
template<int BM1, int BM2, int BK>
__global__ __launch_bounds__(256) void gemm_level(
    const _Float16* __restrict__ Hsum, const _Float16* __restrict__ Hc,
    const _Float16* __restrict__ Wiou, const _Float16* __restrict__ Wf,
    _Float16* __restrict__ houpre, _Float16* __restrict__ fpre,
    int G1, int G2)
{
    constexpr int BMX = (BM1 > BM2) ? BM1 : BM2;
    __shared__ __align__(16) _Float16 ldsA[BMX * BK];
    __shared__ __align__(16) _Float16 ldsB[128 * BK];
    int bx = blockIdx.x;
    if (bx < G1 * 24) {
        int nb = bx / G1, mb = bx % G1;
        gemm_tile<BM1, 128, BK>(Hsum + (long long)mb * BM1 * 1024, 1024,
                                Wiou + (long long)nb * 128 * 1024, 1024,
                                houpre + (long long)mb * BM1 * 3072 + nb * 128, 3072,
                                1024, ldsA, ldsB);
    } else {
        int b2 = bx - G1 * 24;
        int nb = b2 / G2, mb = b2 % G2;
        gemm_tile<BM2, 128, BK>(Hc + (long long)mb * BM2 * 1024, 1024,
                                Wf + (long long)nb * 128 * 1024, 1024,
                                fpre + (long long)mb * BM2 * 1024 + nb * 128, 1024,
                                1024, ldsA, ldsB);
    }
}

// ---------------------------------------------------------------------------
// Leaf fused GEMM+combine: tile 64 leaves x 128 cols, 3 gate accumulators
// (i,o,u), K=320, single-buffered (28 KB LDS). Writes cleaf/h/hsum.
// ---------------------------------------------------------------------------
__global__ __launch_bounds__(256) void leaf_fused(
    const _Float16* __restrict__ x16, const _Float16* __restrict__ Bx,
    _Float16* __restrict__ cleaf, _Float16* __restrict__ hleaf,
    _Float16* __restrict__ hsum)
{
    constexpr int BK = 32, CPR = 4, SWM = 3;
    __shared__ __align__(16) _Float16 lA[64 * BK];
    __shared__ __align__(16) _Float16 lB[384 * BK];
    int tid = threadIdx.x, wave = tid >> 6, lane = tid & 63;
    int kq = (lane >> 4) * 8, rs = lane & 15;
    int wr = (wave >> 1) * 32, wc = (wave & 1) * 64;
    int m0 = blockIdx.x * 64, c0 = blockIdx.y * 128;
    const _Float16* A = x16 + (size_t)(8191 + m0) * XDIM;

    f32x4 acc[3][2][4] = {};
    for (int t = 0; t < 10; ++t) {     // K = 320
        int k0 = t * BK;
        {   // A: 256 chunks, 1/thread
            int c = tid, row = c / CPR, s = (c ^ row) & SWM;
            GLOAD_LDS16(A + (long long)row * XDIM + k0 + s * 8, &lA[(wave * 64) * 8]);
        }
#pragma unroll
        for (int j = 0; j < 6; ++j) {   // B: 1536 chunks (3 gate tiles x 128)
            int c = j * 256 + tid;
            int row = c / CPR, s = (c ^ row) & SWM;
            int g = row >> 7, rr = row & 127;
            GLOAD_LDS16(Bx + (long long)(g * 1024 + c0 + rr) * XDIM + k0 + s * 8,
                        &lB[(j * 256 + wave * 64) * 8]);
        }
        __syncthreads();
        half8 a[2], b[3][4];
#pragma unroll
        for (int mi = 0; mi < 2; ++mi) {
            int r = wr + mi * 16 + rs;
            int s = (kq >> 3) ^ (r & SWM);
            a[mi] = *(const half8*)&lA[r * BK + s * 8];
        }
#pragma unroll
        for (int g = 0; g < 3; ++g)
#pragma unroll
            for (int nj = 0; nj < 4; ++nj) {
                int r = g * 128 + wc + nj * 16 + rs;
                int s = (kq >> 3) ^ (r & SWM);
                b[g][nj] = *(const half8*)&lB[r * BK + s * 8];
            }
#pragma unroll
        for (int g = 0; g < 3; ++g)
#pragma unroll
            for (int mi = 0; mi < 2; ++mi)
#pragma unroll
                for (int nj = 0; nj < 4; ++nj)
                    acc[g][mi][nj] = __builtin_amdgcn_mfma_f32_16x16x32_f16(a[mi], b[g][nj], acc[g][mi][nj], 0, 0, 0);
        __syncthreads();
    }
    int lrb = wr + (lane >> 4) * 4;
#pragma unroll
    for (int mi = 0; mi < 2; ++mi)
#pragma unroll
        for (int nj = 0; nj < 4; ++nj) {
            int col = c0 + wc + nj * 16 + rs;
            float hpair = 0.f;
#pragma unroll
            for (int i = 0; i < 4; ++i) {
                long long l = m0 + lrb + mi * 16 + i;
                float cc = sigf(acc[0][mi][nj][i]) * tanhfast(acc[2][mi][nj][i]);
                float hh = sigf(acc[1][mi][nj][i]) * tanhfast(cc);
                cleaf[l * 1024 + col] = (_Float16)cc;
                hleaf[l * 1024 + col] = (_Float16)hh;
                if (i & 1) hsum[(l >> 1) * 1024 + col] = (_Float16)(hpair + hh);
                else hpair = hh;
            }
        }
}

// ---------------------------------------------------------------------------
// Combine: gates from houpre + Xp(iou cols 0..3071), f per child from fpre +
// Xp(col 3072+), c = i*u + f0*c0 + f1*c1, h = o*tanh(c). Emits c/h/hsum; at
// lvl0 writes d_out = [c;h] f32 instead. Xp stride 4096.
// ---------------------------------------------------------------------------
template<bool C16>
__global__ void combine_level(
    const _Float16* __restrict__ houpre, const _Float16* __restrict__ fpre,
    const void* __restrict__ cprevp,
    const _Float16* __restrict__ Xp,
    float* __restrict__ cout, _Float16* __restrict__ hout, _Float16* __restrict__ hsum,
    int n, int gx0, float* __restrict__ fin)
{
    int idx = blockIdx.x * blockDim.x + threadIdx.x;
    int npairs = (n > 1) ? (n >> 1) : 1;
    if (idx >= npairs * 128) return;
    int r = idx >> 7, m8 = (idx & 127) * 8;
    float hs[8];
#pragma unroll
    for (int j = 0; j < 8; ++j) hs[j] = 0.f;
    int pmax = (n > 1) ? 2 : 1;
    for (int t = 0; t < pmax; ++t) {
        int p = 2 * r + t;
        long long node = gx0 + p;
        half8 phi = *(const half8*)&houpre[(long long)p * 3072 + m8];
        half8 pho = *(const half8*)&houpre[(long long)p * 3072 + 1024 + m8];
        half8 phu = *(const half8*)&houpre[(long long)p * 3072 + 2048 + m8];
        half8 pxi = *(const half8*)&Xp[node * 4096 + m8];
        half8 pxo = *(const half8*)&Xp[node * 4096 + 1024 + m8];
        half8 pxu = *(const half8*)&Xp[node * 4096 + 2048 + m8];
        half8 pxf = *(const half8*)&Xp[node * 4096 + 3072 + m8];
        half8 pf0 = *(const half8*)&fpre[(long long)(2 * p) * 1024 + m8];
        half8 pf1 = *(const half8*)&fpre[(long long)(2 * p + 1) * 1024 + m8];
        float c0[8], c1[8];
        if (C16) {
            const _Float16* cp = (const _Float16*)cprevp;
            half8 a = *(const half8*)&cp[(long long)(2 * p) * 1024 + m8];
            half8 b = *(const half8*)&cp[(long long)(2 * p + 1) * 1024 + m8];
#pragma unroll
            for (int j = 0; j < 8; ++j) { c0[j] = (float)a[j]; c1[j] = (float)b[j]; }
        } else {
            const float* cp = (const float*)cprevp;
            f32x4 a0 = *(const f32x4*)&cp[(long long)(2 * p) * 1024 + m8];
            f32x4 a1 = *(const f32x4*)&cp[(long long)(2 * p) * 1024 + m8 + 4];
            f32x4 b0 = *(const f32x4*)&cp[(long long)(2 * p + 1) * 1024 + m8];
            f32x4 b1 = *(const f32x4*)&cp[(long long)(2 * p + 1) * 1024 + m8 + 4];
#pragma unroll
            for (int j = 0; j < 4; ++j) { c0[j] = a0[j]; c0[j + 4] = a1[j]; c1[j] = b0[j]; c1[j + 4] = b1[j]; }
        }
        float cw[8], hw[8];
#pragma unroll
        for (int j = 0; j < 8; ++j) {
            float i  = sigf((float)phi[j] + (float)pxi[j]);
            float o  = sigf((float)pho[j] + (float)pxo[j]);
            float u  = tanhfast((float)phu[j] + (float)pxu[j]);
            float f0 = sigf((float)pf0[j] + (float)pxf[j]);
            float f1 = sigf((float)pf1[j] + (float)pxf[j]);
            float c = i * u + f0 * c0[j] + f1 * c1[j];
            float h = o * tanhfast(c);
            cw[j] = c; hw[j] = h; hs[j] += h;
        }
        if (fin) {                      // lvl0: write [c;h] f32 to d_out
            f32x4 v0 = {cw[0], cw[1], cw[2], cw[3]}, v1 = {cw[4], cw[5], cw[6], cw[7]};
            f32x4 w0 = {hw[0], hw[1], hw[2], hw[3]}, w1 = {hw[4], hw[5], hw[6], hw[7]};
            *(f32x4*)&fin[m8] = v0;            *(f32x4*)&fin[m8 + 4] = v1;
            *(f32x4*)&fin[1024 + m8] = w0;     *(f32x4*)&fin[1024 + m8 + 4] = w1;
        } else {
            f32x4 v0 = {cw[0], cw[1], cw[2], cw[3]}, v1 = {cw[4], cw[5], cw[6], cw[7]};
            *(f32x4*)&cout[(long long)p * 1024 + m8] = v0;
            *(f32x4*)&cout[(long long)p * 1024 + m8 + 4] = v1;
            half8 hv;
#pragma unroll
            for (int j = 0; j < 8; ++j) hv[j] = (_Float16)hw[j];
            *(half8*)&hout[(long long)p * 1024 + m8] = hv;
        }
    }
    if (!fin) {
        half8 sv;
#pragma unroll
        for (int j = 0; j < 8; ++j) sv[j] = (_Float16)hs[j];
        *(half8*)&hsum[(long long)r * 1024 + m8] = sv;
    }
}

// ---------------------------------------------------------------------------
extern "C" void kernel_launch(void* const* d_in, const int* in_sizes, int n_in,
                              void* d_out, int out_size, void* d_ws, size_t ws_size,
                              hipStream_t stream)
{
    const float* embs = (const float*)d_in[0];
    const float* Wix = (const float*)d_in[1];  const float* bix = (const float*)d_in[2];
    const float* Wih = (const float*)d_in[3];  const float* bih = (const float*)d_in[4];
    const float* Wfx = (const float*)d_in[5];  const float* bfx = (const float*)d_in[6];
    const float* Wfh = (const float*)d_in[7];  const float* bfh = (const float*)d_in[8];
    const float* Wox = (const float*)d_in[9];  const float* box_ = (const float*)d_in[10];
    const float* Woh = (const float*)d_in[11]; const float* boh = (const float*)d_in[12];
    const float* Wux = (const float*)d_in[13]; const float* bux = (const float*)d_in[14];
    const float* Wuh = (const float*)d_in[15]; const float* buh = (const float*)d_in[16];

    char* p = (char*)d_ws;
    auto carve = [&](size_t bytes) -> char* {
        char* r = p; p += (bytes + 255) & ~(size_t)255; return r;
    };
    _Float16* Wiou16 = (_Float16*)carve((size_t)3072 * 1024 * 2);   //   6.3 MB
    _Float16* Wfh16  = (_Float16*)carve((size_t)1024 * 1024 * 2);   //   2.1 MB
    _Float16* Xp     = (_Float16*)carve((size_t)8192 * 4096 * 2);   //  67.1 MB (iou|f)
    _Float16* houpre = (_Float16*)carve((size_t)4096 * 3072 * 2);   //  25.2 MB
    _Float16* fpre   = (_Float16*)carve((size_t)8192 * 1024 * 2);   //  16.8 MB
    _Float16* H_A    = (_Float16*)carve((size_t)8192 * 1024 * 2);   //  16.8 MB
    _Float16* H_B    = (_Float16*)carve((size_t)4096 * 1024 * 2);   //   8.4 MB
    _Float16* HsumA  = (_Float16*)carve((size_t)4096 * 1024 * 2);   //   8.4 MB
    _Float16* HsumB  = (_Float16*)carve((size_t)4096 * 1024 * 2);   //   8.4 MB
    _Float16* Cleaf  = (_Float16*)carve((size_t)8192 * 1024 * 2);   //  16.8 MB
    float*    Cping  = (float*)carve((size_t)4096 * 1024 * 4);      //  16.8 MB
    float*    Cpong  = (float*)carve((size_t)2048 * 1024 * 4);      //   8.4 MB
    // total ~202 MB. Aliases (stream-ordered): x16/Bx live in fpre (13.1 MB
    // needed <= 16.8), dead after leaf_fused; fpre first written at lvl12.
    _Float16* x16 = fpre;
    _Float16* Bx  = fpre + (size_t)16384 * XDIM;

    {   // pack
        long long tot = 3072LL * 1024 + 1024LL * 1024 + 16384LL * XDIM + 4096LL * XDIM;
        pack_kernel<<<dim3((int)((tot + 255) / 256)), dim3(256), 0, stream>>>(
            embs, Wix, bix, Wih, bih, Wfx, bfx, Wfh, bfh,
            Wox, box_, Woh, boh, Wux, bux, Wuh, buh,
            Wiou16, Wfh16, x16, Bx);
    }

    // Xp = x[0:8192] @ [Wix;Wox;Wux;Wfx]^T (+biases), 8192x4096, K=320 — one GEMM
    gemm_f16<128, 128, 32><<<dim3(64, 32), dim3(256), 0, stream>>>(
        x16, XDIM, Bx, XDIM, Xp, 4096, XDIM);
    // Leaf level fused GEMM+combine
    leaf_fused<<<dim3(128, 8), dim3(256), 0, stream>>>(x16, Bx, Cleaf, H_A, HsumA);

    const void* cprev = Cleaf;
    float* cbufs[2] = {Cping, Cpong};
    _Float16* hsums[2] = {HsumA, HsumB};
    int ci = 0, si = 0;
    _Float16* hcur = H_A;
    _Float16* hnext = H_B;

    for (int lvl = 12; lvl >= 0; --lvl) {
        int n = 1 << lvl;
        int G1, G2;
        if (n >= 1024) {
            G1 = n / 128; G2 = 2 * n / 128;
            gemm_level<128, 128, 32><<<dim3(G1 * 24 + G2 * 8), dim3(256), 0, stream>>>(
                hsums[si], hcur, Wiou16, Wfh16, houpre, fpre, G1, G2);
        } else if (n >= 128) {
            G1 = n / 128; G2 = 2 * n / 128;
            gemm_level<128, 128, 128><<<dim3(G1 * 24 + G2 * 8), dim3(256), 0, stream>>>(
                hsums[si], hcur, Wiou16, Wfh16, houpre, fpre, G1, G2);
        } else if (n == 64) {
            G1 = 1; G2 = 1;
            gemm_level<64, 128, 128><<<dim3(G1 * 24 + G2 * 8), dim3(256), 0, stream>>>(
                hsums[si], hcur, Wiou16, Wfh16, houpre, fpre, G1, G2);
        } else {
            G1 = 1; G2 = 1;
            gemm_level<64, 64, 128><<<dim3(G1 * 24 + G2 * 8), dim3(256), 0, stream>>>(
                hsums[si], hcur, Wiou16, Wfh16, houpre, fpre, G1, G2);
        }

        int npairs = (n > 1) ? (n >> 1) : 1;
        int blocks = (npairs * 128 + 255) / 256;
        float* fin = (lvl == 0) ? (float*)d_out : nullptr;
        if (lvl == 12)
            combine_level<true><<<dim3(blocks), dim3(256), 0, stream>>>(
                houpre, fpre, cprev, Xp, cbufs[ci], hnext, hsums[si ^ 1], n, n - 1, fin);
        else
            combine_level<false><<<dim3(blocks), dim3(256), 0, stream>>>(
                houpre, fpre, cprev, Xp, cbufs[ci], hnext, hsums[si ^ 1], n, n - 1, fin);

        cprev = cbufs[ci];
        ci ^= 1; si ^= 1;
        _Float16* tmp = hcur; hcur = hnext; hnext = tmp;
    }
}